// Round 2
// baseline (241.713 us; speedup 1.0000x reference)
//
#include <hip/hip_runtime.h>

// MomentumLIF: x[N,T,D] f32 -> spikes[N,T,D] f32 (0/1)
//   v_t = mom*v + x_t - lamb*u ; u_t = 0.5*u + v_t ; s = (u>=1); u *= (1-s)
// Sequential over T (recurrence), parallel over all N*D chains.
// R2: 1 element per thread -> 8192 waves -> 32 waves/CU (was 8). The kernel
// is HBM-latency-bound at low occupancy (R1: 18% occ, 2.5 TB/s); full
// occupancy + unroll-8 load pipelining should push toward the ~6.3 TB/s
// achievable ceiling.

#define N_ 64
#define T_ 64
#define D_ 8192

__global__ __launch_bounds__(256) void MomentumLIF_kernel(
    const float* __restrict__ x,
    const float* __restrict__ momp,
    const float* __restrict__ lambp,
    float* __restrict__ out)
{
    // Match numpy f32 semantics exactly: no FMA contraction anywhere in here.
#pragma clang fp contract(off)
    const float mom  = momp[0];
    const float lamb = lambp[0];
    const float decay = 0.5f;   // 1 - 1/TAU, exact

    const int tid = blockIdx.x * blockDim.x + threadIdx.x;  // [0, N*D)
    const int n = tid >> 13;         // / D_
    const int d = tid & (D_ - 1);

    const float* __restrict__ xp = x   + (size_t)n * T_ * D_ + d;
    float*       __restrict__ op = out + (size_t)n * T_ * D_ + d;

    float u = 0.f, v = 0.f;

#pragma unroll 8
    for (int t = 0; t < T_; ++t) {
        const float xt = xp[(size_t)t * D_];

        float t1 = mom * v;            // separately rounded, matches numpy
        float t2 = lamb * u;
        v = (t1 + xt) - t2;
        u = decay * u + v;
        const bool sp = (u >= 1.0f);
        op[(size_t)t * D_] = sp ? 1.0f : 0.0f;
        u = sp ? 0.0f : u;             // u*(1-s) is exactly this select
    }
}

extern "C" void kernel_launch(void* const* d_in, const int* in_sizes, int n_in,
                              void* d_out, int out_size, void* d_ws, size_t ws_size,
                              hipStream_t stream) {
    const float* x    = (const float*)d_in[0];
    const float* momp = (const float*)d_in[1];
    const float* lamb = (const float*)d_in[2];
    float* out = (float*)d_out;

    const int threads = N_ * D_;         // 524288 chains, 1 per thread
    dim3 block(256);
    dim3 grid(threads / 256);            // 2048 blocks -> 8 blocks/CU
    hipLaunchKernelGGL(MomentumLIF_kernel, grid, block, 0, stream,
                       x, momp, lamb, out);
}

// Round 3
// 233.378 us; speedup vs baseline: 1.0357x; 1.0357x over previous
//
#include <hip/hip_runtime.h>

// MomentumLIF: x[N,T,D] f32 -> spikes[N,T,D] f32 (0/1)
//   v_t = mom*v + x_t - lamb*u ; u_t = 0.5*u + v_t ; s = (u>=1); u *= (1-s)
// Sequential over T (recurrence), parallel over all N*D chains.
//
// R3: R2 showed occupancy 18->68% changed NOTHING (82us both) -> per-wave
// latency-bound: compiler only kept ~1-2 loads in flight (VGPR=20). This
// version forces an explicit 8-deep rotating prefetch (full T-unroll makes
// rotation indices compile-time), so loads run 8 iterations ahead of use.
// Spike stores are nontemporal so the 128MB write stream doesn't evict the
// L3-resident x (harness restore leaves x in L3; R2 FETCH was already half-
// absorbed).

#define N_ 64
#define T_ 64
#define D_ 8192
#define PF 8   // prefetch depth (iterations ahead)

__global__ __launch_bounds__(256) void MomentumLIF_kernel(
    const float* __restrict__ x,
    const float* __restrict__ momp,
    const float* __restrict__ lambp,
    float* __restrict__ out)
{
    // Match numpy f32 semantics exactly: no FMA contraction anywhere in here.
#pragma clang fp contract(off)
    const float mom  = momp[0];
    const float lamb = lambp[0];
    const float decay = 0.5f;   // 1 - 1/TAU, exact

    const int tid = blockIdx.x * blockDim.x + threadIdx.x;  // [0, N*D)
    const int n = tid >> 13;         // / D_
    const int d = tid & (D_ - 1);

    const float* __restrict__ xp = x   + (size_t)n * T_ * D_ + d;
    float*       __restrict__ op = out + (size_t)n * T_ * D_ + d;

    float u = 0.f, v = 0.f;
    float xbuf[PF];

    // Prologue: fill the pipeline 8 deep.
#pragma unroll
    for (int i = 0; i < PF; ++i)
        xbuf[i] = xp[(size_t)i * D_];

    // Main loop, fully unrolled so xbuf[t & (PF-1)] is a constant register
    // and every iteration issues the t+PF load before consuming t.
#pragma unroll
    for (int t = 0; t < T_; ++t) {
        const float xt = xbuf[t & (PF - 1)];
        if (t + PF < T_)
            xbuf[t & (PF - 1)] = xp[(size_t)(t + PF) * D_];

        float t1 = mom * v;            // separately rounded, matches numpy
        float t2 = lamb * u;
        v = (t1 + xt) - t2;
        u = decay * u + v;
        const bool sp = (u >= 1.0f);
        __builtin_nontemporal_store(sp ? 1.0f : 0.0f, op + (size_t)t * D_);
        u = sp ? 0.0f : u;             // u*(1-s) is exactly this select
    }
}

extern "C" void kernel_launch(void* const* d_in, const int* in_sizes, int n_in,
                              void* d_out, int out_size, void* d_ws, size_t ws_size,
                              hipStream_t stream) {
    const float* x    = (const float*)d_in[0];
    const float* momp = (const float*)d_in[1];
    const float* lamb = (const float*)d_in[2];
    float* out = (float*)d_out;

    const int threads = N_ * D_;         // 524288 chains, 1 per thread
    dim3 block(256);
    dim3 grid(threads / 256);            // 2048 blocks -> 8 blocks/CU
    hipLaunchKernelGGL(MomentumLIF_kernel, grid, block, 0, stream,
                       x, momp, lamb, out);
}